// Round 5
// baseline (436.707 us; speedup 1.0000x reference)
//
#include <hip/hip_runtime.h>
#include <hip/hip_fp16.h>
#include <stdint.h>
#include <math.h>

#define N_TOK 4096
#define DIM   512
#define HID   2048
#define NE    8
#define NSLOT (2 * N_TOK)

#define HALF_LOG_2PI 0.91893853320467274178f

using half8 = __attribute__((ext_vector_type(8))) _Float16;
using f32x4 = __attribute__((ext_vector_type(4))) float;
using u16x8 = __attribute__((ext_vector_type(8))) unsigned short;

__device__ __forceinline__ float gelu_exact(float v) {
  return 0.5f * v * (1.0f + erff(v * 0.70710678118654752440f));
}

// split fp32 into fp16 hi + fp16 lo (residual), packed u32 = hi | lo<<16
__device__ __forceinline__ uint32_t split_pack(float x) {
  __half h = __float2half(x);
  float r = x - __half2float(h);
  return (uint32_t)__half_as_ushort(h) | ((uint32_t)__half_as_ushort(__float2half(r)) << 16);
}

// unpack 8 packed u32 (k..k+7) into hi-vector and lo-vector of 8 ushorts
__device__ __forceinline__ void unpack8(const uint4 a, const uint4 b,
                                        u16x8& h, u16x8& l) {
  h = (u16x8){(unsigned short)a.x, (unsigned short)a.y,
              (unsigned short)a.z, (unsigned short)a.w,
              (unsigned short)b.x, (unsigned short)b.y,
              (unsigned short)b.z, (unsigned short)b.w};
  l = (u16x8){(unsigned short)(a.x >> 16), (unsigned short)(a.y >> 16),
              (unsigned short)(a.z >> 16), (unsigned short)(a.w >> 16),
              (unsigned short)(b.x >> 16), (unsigned short)(b.y >> 16),
              (unsigned short)(b.z >> 16), (unsigned short)(b.w >> 16)};
}

// ---------------- router: 1 wave per token ----------------
__global__ __launch_bounds__(256) void router_kernel(
    const float* __restrict__ x, const float* __restrict__ mus,
    const float* __restrict__ ls, float* __restrict__ out_logp,
    float* __restrict__ out_w, float* __restrict__ out_idx,
    float* __restrict__ wts, int* __restrict__ bucket, int* __restrict__ counts)
{
  const int lane = threadIdx.x & 63;
  const int n = blockIdx.x * 4 + (threadIdx.x >> 6);

  const float* xr = x + (size_t)n * DIM;
  const float4 xv0 = *(const float4*)(xr + lane * 4);
  const float4 xv1 = *(const float4*)(xr + 256 + lane * 4);

  float logp[NE];
#pragma unroll
  for (int e = 0; e < NE; ++e) {
    const float* mr = mus + e * DIM;
    const float* lr = ls + e * DIM;
    const float4 m0 = *(const float4*)(mr + lane * 4);
    const float4 m1 = *(const float4*)(mr + 256 + lane * 4);
    const float4 l0 = *(const float4*)(lr + lane * 4);
    const float4 l1 = *(const float4*)(lr + 256 + lane * 4);
    float s = 0.0f, z;
    z = (xv0.x - m0.x) * expf(-l0.x); s += 0.5f*z*z + l0.x;
    z = (xv0.y - m0.y) * expf(-l0.y); s += 0.5f*z*z + l0.y;
    z = (xv0.z - m0.z) * expf(-l0.z); s += 0.5f*z*z + l0.z;
    z = (xv0.w - m0.w) * expf(-l0.w); s += 0.5f*z*z + l0.w;
    z = (xv1.x - m1.x) * expf(-l1.x); s += 0.5f*z*z + l1.x;
    z = (xv1.y - m1.y) * expf(-l1.y); s += 0.5f*z*z + l1.y;
    z = (xv1.z - m1.z) * expf(-l1.z); s += 0.5f*z*z + l1.z;
    z = (xv1.w - m1.w) * expf(-l1.w); s += 0.5f*z*z + l1.w;
#pragma unroll
    for (int off = 32; off > 0; off >>= 1) s += __shfl_xor(s, off);
    logp[e] = -s - DIM * HALF_LOG_2PI;
  }

  // top-2 (ties toward lower index, matching jax.lax.top_k)
  float best = -INFINITY, second = -INFINITY;
  int bi = 0, si = 0;
#pragma unroll
  for (int e = 0; e < NE; ++e) {
    float v = logp[e];
    if (v > best) { second = best; si = bi; best = v; bi = e; }
    else if (v > second) { second = v; si = e; }
  }
  float ew = expf(second - best);
  float w0 = 1.0f / (1.0f + ew);
  float w1 = ew * w0;

  // static-indexed stores (runtime-indexed logp[] would spill to scratch)
#pragma unroll
  for (int e = 0; e < NE; ++e)
    if (lane == e) out_logp[(size_t)n * NE + e] = logp[e];

  if (lane == 0) {
    out_w[n * 2 + 0] = w0;
    out_w[n * 2 + 1] = w1;
    out_idx[n * 2 + 0] = (float)bi;
    out_idx[n * 2 + 1] = (float)si;
    wts[n * 2 + 0] = w0;
    wts[n * 2 + 1] = w1;
    int p0 = atomicAdd(&counts[bi], 1);
    bucket[bi * N_TOK + p0] = n * 2 + 0;
    int p1 = atomicAdd(&counts[si], 1);
    bucket[si * N_TOK + p1] = n * 2 + 1;
  }
}

__global__ void scan_kernel(const int* __restrict__ counts, int* __restrict__ offs) {
  int acc = 0;
  for (int e = 0; e < NE; ++e) { offs[e] = acc; acc += counts[e]; }
}

// ---------------- x pre-split: f32 -> packed hi|lo ----------------
__global__ __launch_bounds__(256) void x_split(
    const float* __restrict__ x, uint32_t* __restrict__ x2)
{
  const size_t i = (size_t)blockIdx.x * 256 + threadIdx.x;
  float4 v = ((const float4*)x)[i];
  uint4 o;
  o.x = split_pack(v.x); o.y = split_pack(v.y);
  o.z = split_pack(v.z); o.w = split_pack(v.w);
  ((uint4*)x2)[i] = o;
}

// ---------------- W transpose + fp16 hi/lo split ----------------
// W: [e][K][N] f32  ->  Wt: [e][N][K] u32 (packed hi|lo<<16)
__global__ __launch_bounds__(256) void transpose_split(
    const float* __restrict__ W, uint32_t* __restrict__ Wt, int K, int N)
{
  const int e = blockIdx.z;
  const int k0 = blockIdx.y * 64, n0 = blockIdx.x * 64;
  __shared__ float tile[64][65];
  const int t = threadIdx.x;
  const int r = t >> 2, c0 = t & 3;

  const float* src = W + ((size_t)e * K + k0 + r) * N + n0;
#pragma unroll
  for (int j = 0; j < 4; ++j) {
    const int col = (c0 + j * 4) * 4;
    float4 v = *(const float4*)(src + col);
    tile[r][col + 0] = v.x; tile[r][col + 1] = v.y;
    tile[r][col + 2] = v.z; tile[r][col + 3] = v.w;
  }
  __syncthreads();
  uint32_t* dst = Wt + ((size_t)e * N + n0 + r) * K + k0;
#pragma unroll
  for (int j = 0; j < 4; ++j) {
    const int kc = (c0 + j * 4) * 4;
    uint4 o;
    o.x = split_pack(tile[kc + 0][r]);
    o.y = split_pack(tile[kc + 1][r]);
    o.z = split_pack(tile[kc + 2][r]);
    o.w = split_pack(tile[kc + 3][r]);
    *(uint4*)(dst + kc) = o;
  }
}

// ---------------- MFMA grouped GEMM, 128x128 tile, BK=32 ----------------
// LDS rows: 32 data + 8 pad ushorts (80B). Stride 20 words (gcd(20,32)=4):
//  - b128 frag reads: start quads (20*row+4*kg)%32 tile all 32 banks, 8
//    accesses/bank = optimal.
//  - staging writes MUST be 16B (u16x8): start banks (20m+8p+4c)%32 tile all
//    32 banks, 8/bank = optimal. (8B writes would hit only 16 banks = 2x.)
#define LR 40

// pass 1: h2[slot,:] = splitpack(gelu(x[tok] @ W1[e] + b1[e]))
__global__ __launch_bounds__(256) void mlp1_mfma(
    const uint32_t* __restrict__ x2, const uint32_t* __restrict__ W1t,
    const float* __restrict__ b1, const int* __restrict__ bucket,
    const int* __restrict__ counts, const int* __restrict__ offs,
    uint32_t* __restrict__ h2)
{
  const int e = blockIdx.z;
  const int cnt = counts[e];
  const int i0 = blockIdx.y * 128;
  if (i0 >= cnt) return;
  const int n0 = blockIdx.x * 128;
  const int t = threadIdx.x;
  const int lane = t & 63, w = t >> 6;
  const int wr = w >> 1, wc = w & 1;
  const int fl = lane & 15, kg = lane >> 4;

  __shared__ unsigned short Ah[128 * LR], Al[128 * LR];
  __shared__ unsigned short Bh[128 * LR], Bl[128 * LR];

  // staging: 2 threads per row, 16 k-elements each
  const int s_row = t >> 1;
  const int s_kh = (t & 1) * 16;
  const int sbase = s_row * LR + s_kh;

  const bool aval = (i0 + s_row) < cnt;
  const int tok = aval ? (bucket[e * N_TOK + i0 + s_row] >> 1) : 0;
  const uint32_t* ap = x2 + (size_t)tok * DIM + s_kh;
  const uint32_t* bp = W1t + ((size_t)e * HID + n0 + s_row) * DIM + s_kh;

  f32x4 acc[4][4] = {};

  uint4 ar[4], br[4];
#pragma unroll
  for (int j = 0; j < 4; ++j) {
    ar[j] = *(const uint4*)(ap + j * 4);
    br[j] = *(const uint4*)(bp + j * 4);
  }

  for (int k0 = 0; k0 < DIM; k0 += 32) {
    __syncthreads();
    {
      u16x8 h0, l0, h1, l1;
      unpack8(ar[0], ar[1], h0, l0);
      unpack8(ar[2], ar[3], h1, l1);
      *(u16x8*)&Ah[sbase] = h0;  *(u16x8*)&Ah[sbase + 8] = h1;
      *(u16x8*)&Al[sbase] = l0;  *(u16x8*)&Al[sbase + 8] = l1;
      unpack8(br[0], br[1], h0, l0);
      unpack8(br[2], br[3], h1, l1);
      *(u16x8*)&Bh[sbase] = h0;  *(u16x8*)&Bh[sbase + 8] = h1;
      *(u16x8*)&Bl[sbase] = l0;  *(u16x8*)&Bl[sbase + 8] = l1;
    }
    __syncthreads();
    if (k0 + 32 < DIM) {
#pragma unroll
      for (int j = 0; j < 4; ++j) {
        ar[j] = *(const uint4*)(ap + k0 + 32 + j * 4);
        br[j] = *(const uint4*)(bp + k0 + 32 + j * 4);
      }
    }
    const int abase = (wr * 64 + fl) * LR + kg * 8;
    const int bbase = (wc * 64 + fl) * LR + kg * 8;
    half8 ah[4], al_[4], bh[4], bl_[4];
#pragma unroll
    for (int f = 0; f < 4; ++f) {
      ah[f]  = *(const half8*)&Ah[abase + f * 16 * LR];
      al_[f] = *(const half8*)&Al[abase + f * 16 * LR];
      bh[f]  = *(const half8*)&Bh[bbase + f * 16 * LR];
      bl_[f] = *(const half8*)&Bl[bbase + f * 16 * LR];
    }
    // 3-term split product; dependent MFMAs on same acc separated by 4
#pragma unroll
    for (int fc = 0; fc < 4; ++fc) {
#pragma unroll
      for (int fr = 0; fr < 4; ++fr)
        acc[fr][fc] = __builtin_amdgcn_mfma_f32_16x16x32_f16(ah[fr], bh[fc], acc[fr][fc], 0, 0, 0);
#pragma unroll
      for (int fr = 0; fr < 4; ++fr)
        acc[fr][fc] = __builtin_amdgcn_mfma_f32_16x16x32_f16(al_[fr], bh[fc], acc[fr][fc], 0, 0, 0);
#pragma unroll
      for (int fr = 0; fr < 4; ++fr)
        acc[fr][fc] = __builtin_amdgcn_mfma_f32_16x16x32_f16(ah[fr], bl_[fc], acc[fr][fc], 0, 0, 0);
    }
  }

  // epilogue: bias + gelu + split-pack (C/D map: col=lane&15, row=kg*4+q)
  const int hbase = offs[e] + i0;
  const float* b1e = b1 + (size_t)e * HID;
  float bs[4];
#pragma unroll
  for (int fc = 0; fc < 4; ++fc) bs[fc] = b1e[n0 + wc * 64 + fc * 16 + fl];
#pragma unroll
  for (int fr = 0; fr < 4; ++fr)
#pragma unroll
    for (int q = 0; q < 4; ++q) {
      const int lr = wr * 64 + fr * 16 + kg * 4 + q;
      if (i0 + lr < cnt) {
        uint32_t* hr = h2 + (size_t)(hbase + lr) * HID + n0 + wc * 64 + fl;
#pragma unroll
        for (int fc = 0; fc < 4; ++fc)
          hr[fc * 16] = split_pack(gelu_exact(acc[fr][fc][q] + bs[fc]));
      }
    }
}

// pass 2: y[tok,:] += w * (h[slot] @ W2[e] + b2[e])
__global__ __launch_bounds__(256) void mlp2_mfma(
    const uint32_t* __restrict__ h2, const uint32_t* __restrict__ W2t,
    const float* __restrict__ b2, const int* __restrict__ bucket,
    const int* __restrict__ counts, const int* __restrict__ offs,
    const float* __restrict__ wts, float* __restrict__ y)
{
  const int e = blockIdx.z;
  const int cnt = counts[e];
  const int i0 = blockIdx.y * 128;
  if (i0 >= cnt) return;
  const int n0 = blockIdx.x * 128;
  const int t = threadIdx.x;
  const int lane = t & 63, w = t >> 6;
  const int wr = w >> 1, wc = w & 1;
  const int fl = lane & 15, kg = lane >> 4;

  __shared__ unsigned short Ah[128 * LR], Al[128 * LR];
  __shared__ unsigned short Bh[128 * LR], Bl[128 * LR];

  const int s_row = t >> 1;
  const int s_kh = (t & 1) * 16;
  const int sbase = s_row * LR + s_kh;

  const bool aval = (i0 + s_row) < cnt;
  const int aslot = offs[e] + (aval ? i0 + s_row : 0);
  const uint32_t* ap = h2 + (size_t)aslot * HID + s_kh;
  const uint32_t* bp = W2t + ((size_t)e * DIM + n0 + s_row) * HID + s_kh;

  f32x4 acc[4][4] = {};

  uint4 ar[4], br[4];
#pragma unroll
  for (int j = 0; j < 4; ++j) {
    ar[j] = *(const uint4*)(ap + j * 4);
    br[j] = *(const uint4*)(bp + j * 4);
  }

  for (int k0 = 0; k0 < HID; k0 += 32) {
    __syncthreads();
    {
      u16x8 h0, l0, h1, l1;
      unpack8(ar[0], ar[1], h0, l0);
      unpack8(ar[2], ar[3], h1, l1);
      *(u16x8*)&Ah[sbase] = h0;  *(u16x8*)&Ah[sbase + 8] = h1;
      *(u16x8*)&Al[sbase] = l0;  *(u16x8*)&Al[sbase + 8] = l1;
      unpack8(br[0], br[1], h0, l0);
      unpack8(br[2], br[3], h1, l1);
      *(u16x8*)&Bh[sbase] = h0;  *(u16x8*)&Bh[sbase + 8] = h1;
      *(u16x8*)&Bl[sbase] = l0;  *(u16x8*)&Bl[sbase + 8] = l1;
    }
    __syncthreads();
    if (k0 + 32 < HID) {
#pragma unroll
      for (int j = 0; j < 4; ++j) {
        ar[j] = *(const uint4*)(ap + k0 + 32 + j * 4);
        br[j] = *(const uint4*)(bp + k0 + 32 + j * 4);
      }
    }
    const int abase = (wr * 64 + fl) * LR + kg * 8;
    const int bbase = (wc * 64 + fl) * LR + kg * 8;
    half8 ah[4], al_[4], bh[4], bl_[4];
#pragma unroll
    for (int f = 0; f < 4; ++f) {
      ah[f]  = *(const half8*)&Ah[abase + f * 16 * LR];
      al_[f] = *(const half8*)&Al[abase + f * 16 * LR];
      bh[f]  = *(const half8*)&Bh[bbase + f * 16 * LR];
      bl_[f] = *(const half8*)&Bl[bbase + f * 16 * LR];
    }
#pragma unroll
    for (int fc = 0; fc < 4; ++fc) {
#pragma unroll
      for (int fr = 0; fr < 4; ++fr)
        acc[fr][fc] = __builtin_amdgcn_mfma_f32_16x16x32_f16(ah[fr], bh[fc], acc[fr][fc], 0, 0, 0);
#pragma unroll
      for (int fr = 0; fr < 4; ++fr)
        acc[fr][fc] = __builtin_amdgcn_mfma_f32_16x16x32_f16(al_[fr], bh[fc], acc[fr][fc], 0, 0, 0);
#pragma unroll
      for (int fr = 0; fr < 4; ++fr)
        acc[fr][fc] = __builtin_amdgcn_mfma_f32_16x16x32_f16(ah[fr], bl_[fc], acc[fr][fc], 0, 0, 0);
    }
  }

  const float* b2e = b2 + (size_t)e * DIM;
  float bs[4];
#pragma unroll
  for (int fc = 0; fc < 4; ++fc) bs[fc] = b2e[n0 + wc * 64 + fc * 16 + fl];
#pragma unroll
  for (int fr = 0; fr < 4; ++fr)
#pragma unroll
    for (int q = 0; q < 4; ++q) {
      const int lr = wr * 64 + fr * 16 + kg * 4 + q;
      if (i0 + lr < cnt) {
        const int ent = bucket[e * N_TOK + i0 + lr];
        const int tk = ent >> 1;
        const float wgt = wts[ent];
        float* yr = y + (size_t)tk * DIM + n0 + wc * 64 + fl;
#pragma unroll
        for (int fc = 0; fc < 4; ++fc)
          atomicAdd(yr + fc * 16, wgt * (acc[fr][fc][q] + bs[fc]));
      }
    }
}

extern "C" void kernel_launch(void* const* d_in, const int* in_sizes, int n_in,
                              void* d_out, int out_size, void* d_ws, size_t ws_size,
                              hipStream_t stream) {
  const float* x   = (const float*)d_in[0];
  const float* mus = (const float*)d_in[1];
  const float* ls  = (const float*)d_in[2];
  const float* W1  = (const float*)d_in[3];
  const float* b1  = (const float*)d_in[4];
  const float* W2  = (const float*)d_in[5];
  const float* b2  = (const float*)d_in[6];

  float* out      = (float*)d_out;
  float* y        = out;                           // [N_TOK, DIM]
  float* out_logp = out + (size_t)N_TOK * DIM;     // [N_TOK, NE]
  float* out_w    = out_logp + (size_t)N_TOK * NE; // [N_TOK, 2]
  float* out_idx  = out_w + (size_t)N_TOK * 2;     // [N_TOK, 2] (as float)

  // workspace layout
  uint32_t* W1t = (uint32_t*)d_ws;                  // [NE][HID][DIM] u32  33.5MB
  uint32_t* W2t = W1t + (size_t)NE * HID * DIM;     // [NE][DIM][HID] u32  33.5MB
  uint32_t* h2  = W2t + (size_t)NE * DIM * HID;     // [NSLOT][HID]  u32   67.1MB
  uint32_t* x2  = h2 + (size_t)NSLOT * HID;         // [N_TOK][DIM]  u32    8.4MB
  int* bucket   = (int*)(x2 + (size_t)N_TOK * DIM); // [NE][N_TOK]
  float* wts    = (float*)(bucket + NE * N_TOK);    // [N_TOK][2]
  int* counts   = (int*)(wts + 2 * N_TOK);          // [NE]
  int* offs     = counts + NE;                      // [NE]

  hipMemsetAsync(y, 0, (size_t)N_TOK * DIM * sizeof(float), stream);
  hipMemsetAsync(counts, 0, NE * sizeof(int), stream);

  router_kernel<<<N_TOK / 4, 256, 0, stream>>>(x, mus, ls, out_logp, out_w,
                                               out_idx, wts, bucket, counts);
  scan_kernel<<<1, 1, 0, stream>>>(counts, offs);

  x_split<<<(N_TOK * DIM / 4) / 256, 256, 0, stream>>>(x, x2);
  transpose_split<<<dim3(HID / 64, DIM / 64, NE), 256, 0, stream>>>(W1, W1t, DIM, HID);
  transpose_split<<<dim3(DIM / 64, HID / 64, NE), 256, 0, stream>>>(W2, W2t, HID, DIM);

  mlp1_mfma<<<dim3(HID / 128, N_TOK / 128, NE), 256, 0, stream>>>(
      x2, W1t, b1, bucket, counts, offs, h2);
  mlp2_mfma<<<dim3(DIM / 128, N_TOK / 128, NE), 256, 0, stream>>>(
      h2, W2t, b2, bucket, counts, offs, wts, y);
}

// Round 8
// 435.865 us; speedup vs baseline: 1.0019x; 1.0019x over previous
//
#include <hip/hip_runtime.h>
#include <hip/hip_fp16.h>
#include <stdint.h>
#include <math.h>

#define N_TOK 4096
#define DIM   512
#define HID   2048
#define NE    8
#define NSLOT (2 * N_TOK)
#define KS    4            // split-K factor for mlp2

#define HALF_LOG_2PI 0.91893853320467274178f

using half8 = __attribute__((ext_vector_type(8))) _Float16;
using f32x4 = __attribute__((ext_vector_type(4))) float;
using u16x8 = __attribute__((ext_vector_type(8))) unsigned short;

__device__ __forceinline__ float gelu_exact(float v) {
  return 0.5f * v * (1.0f + erff(v * 0.70710678118654752440f));
}

// split fp32 into fp16 hi + fp16 lo (residual), packed u32 = hi | lo<<16
__device__ __forceinline__ uint32_t split_pack(float x) {
  __half h = __float2half(x);
  float r = x - __half2float(h);
  return (uint32_t)__half_as_ushort(h) | ((uint32_t)__half_as_ushort(__float2half(r)) << 16);
}

// unpack 8 packed u32 (k..k+7) into hi-vector and lo-vector of 8 ushorts
__device__ __forceinline__ void unpack8(const uint4 a, const uint4 b,
                                        u16x8& h, u16x8& l) {
  h = (u16x8){(unsigned short)a.x, (unsigned short)a.y,
              (unsigned short)a.z, (unsigned short)a.w,
              (unsigned short)b.x, (unsigned short)b.y,
              (unsigned short)b.z, (unsigned short)b.w};
  l = (u16x8){(unsigned short)(a.x >> 16), (unsigned short)(a.y >> 16),
              (unsigned short)(a.z >> 16), (unsigned short)(a.w >> 16),
              (unsigned short)(b.x >> 16), (unsigned short)(b.y >> 16),
              (unsigned short)(b.z >> 16), (unsigned short)(b.w >> 16)};
}

// ---------------- router: 1 wave per token ----------------
__global__ __launch_bounds__(256) void router_kernel(
    const float* __restrict__ x, const float* __restrict__ mus,
    const float* __restrict__ ls, float* __restrict__ out_logp,
    float* __restrict__ out_w, float* __restrict__ out_idx,
    float* __restrict__ wts, int* __restrict__ bucket, int* __restrict__ counts)
{
  const int lane = threadIdx.x & 63;
  const int n = blockIdx.x * 4 + (threadIdx.x >> 6);

  const float* xr = x + (size_t)n * DIM;
  const float4 xv0 = *(const float4*)(xr + lane * 4);
  const float4 xv1 = *(const float4*)(xr + 256 + lane * 4);

  float logp[NE];
#pragma unroll
  for (int e = 0; e < NE; ++e) {
    const float* mr = mus + e * DIM;
    const float* lr = ls + e * DIM;
    const float4 m0 = *(const float4*)(mr + lane * 4);
    const float4 m1 = *(const float4*)(mr + 256 + lane * 4);
    const float4 l0 = *(const float4*)(lr + lane * 4);
    const float4 l1 = *(const float4*)(lr + 256 + lane * 4);
    float s = 0.0f, z;
    z = (xv0.x - m0.x) * expf(-l0.x); s += 0.5f*z*z + l0.x;
    z = (xv0.y - m0.y) * expf(-l0.y); s += 0.5f*z*z + l0.y;
    z = (xv0.z - m0.z) * expf(-l0.z); s += 0.5f*z*z + l0.z;
    z = (xv0.w - m0.w) * expf(-l0.w); s += 0.5f*z*z + l0.w;
    z = (xv1.x - m1.x) * expf(-l1.x); s += 0.5f*z*z + l1.x;
    z = (xv1.y - m1.y) * expf(-l1.y); s += 0.5f*z*z + l1.y;
    z = (xv1.z - m1.z) * expf(-l1.z); s += 0.5f*z*z + l1.z;
    z = (xv1.w - m1.w) * expf(-l1.w); s += 0.5f*z*z + l1.w;
#pragma unroll
    for (int off = 32; off > 0; off >>= 1) s += __shfl_xor(s, off);
    logp[e] = -s - DIM * HALF_LOG_2PI;
  }

  // top-2 (ties toward lower index, matching jax.lax.top_k)
  float best = -INFINITY, second = -INFINITY;
  int bi = 0, si = 0;
#pragma unroll
  for (int e = 0; e < NE; ++e) {
    float v = logp[e];
    if (v > best) { second = best; si = bi; best = v; bi = e; }
    else if (v > second) { second = v; si = e; }
  }
  float ew = expf(second - best);
  float w0 = 1.0f / (1.0f + ew);
  float w1 = ew * w0;

  // static-indexed stores (runtime-indexed logp[] would spill to scratch)
#pragma unroll
  for (int e = 0; e < NE; ++e)
    if (lane == e) out_logp[(size_t)n * NE + e] = logp[e];

  if (lane == 0) {
    out_w[n * 2 + 0] = w0;
    out_w[n * 2 + 1] = w1;
    out_idx[n * 2 + 0] = (float)bi;
    out_idx[n * 2 + 1] = (float)si;
    wts[n * 2 + 0] = w0;
    wts[n * 2 + 1] = w1;
    int p0 = atomicAdd(&counts[bi], 1);
    bucket[bi * N_TOK + p0] = n * 2 + 0;
    int p1 = atomicAdd(&counts[si], 1);
    bucket[si * N_TOK + p1] = n * 2 + 1;
  }
}

__global__ void scan_kernel(const int* __restrict__ counts, int* __restrict__ offs) {
  int acc = 0;
  for (int e = 0; e < NE; ++e) { offs[e] = acc; acc += counts[e]; }
}

// ---------------- x pre-split: f32 -> packed hi|lo ----------------
__global__ __launch_bounds__(256) void x_split(
    const float* __restrict__ x, uint32_t* __restrict__ x2)
{
  const size_t i = (size_t)blockIdx.x * 256 + threadIdx.x;
  float4 v = ((const float4*)x)[i];
  uint4 o;
  o.x = split_pack(v.x); o.y = split_pack(v.y);
  o.z = split_pack(v.z); o.w = split_pack(v.w);
  ((uint4*)x2)[i] = o;
}

// ---------------- W transpose + fp16 hi/lo split ----------------
// W: [e][K][N] f32  ->  Wt: [e][N][K] u32 (packed hi|lo<<16)
__global__ __launch_bounds__(256) void transpose_split(
    const float* __restrict__ W, uint32_t* __restrict__ Wt, int K, int N)
{
  const int e = blockIdx.z;
  const int k0 = blockIdx.y * 64, n0 = blockIdx.x * 64;
  __shared__ float tile[64][65];
  const int t = threadIdx.x;
  const int r = t >> 2, c0 = t & 3;

  const float* src = W + ((size_t)e * K + k0 + r) * N + n0;
#pragma unroll
  for (int j = 0; j < 4; ++j) {
    const int col = (c0 + j * 4) * 4;
    float4 v = *(const float4*)(src + col);
    tile[r][col + 0] = v.x; tile[r][col + 1] = v.y;
    tile[r][col + 2] = v.z; tile[r][col + 3] = v.w;
  }
  __syncthreads();
  uint32_t* dst = Wt + ((size_t)e * N + n0 + r) * K + k0;
#pragma unroll
  for (int j = 0; j < 4; ++j) {
    const int kc = (c0 + j * 4) * 4;
    uint4 o;
    o.x = split_pack(tile[kc + 0][r]);
    o.y = split_pack(tile[kc + 1][r]);
    o.z = split_pack(tile[kc + 2][r]);
    o.w = split_pack(tile[kc + 3][r]);
    *(uint4*)(dst + kc) = o;
  }
}

// ---------------- MFMA grouped GEMM, 128x128 tile, BK=32 ----------------
// LDS: linear 32-ushort (64B) rows, XOR chunk swizzle: 16B chunk c at row r
// stored at c ^ h(r), h(r) = (r ^ (r>>2)) & 3. Bijective per row, keeps 16B
// alignment, spreads quarter-wave accesses to the 2-cycle bank minimum.
// h(r) depends only on r mod 16 => loop-invariant per thread for reads+writes.
#define LROW 32

// pass 1: h2[slot,:] = splitpack(gelu(x[tok] @ W1[e] + b1[e]))
__global__ __launch_bounds__(256) void mlp1_mfma(
    const uint32_t* __restrict__ x2, const uint32_t* __restrict__ W1t,
    const float* __restrict__ b1, const int* __restrict__ bucket,
    const int* __restrict__ counts, const int* __restrict__ offs,
    uint32_t* __restrict__ h2)
{
  const int e = blockIdx.z;
  const int cnt = counts[e];
  const int i0 = blockIdx.y * 128;
  if (i0 >= cnt) return;
  const int n0 = blockIdx.x * 128;
  const int t = threadIdx.x;
  const int lane = t & 63, w = t >> 6;
  const int wr = w >> 1, wc = w & 1;
  const int fl = lane & 15, kg = lane >> 4;

  __shared__ unsigned short Ah[128 * LROW], Al[128 * LROW];
  __shared__ unsigned short Bh[128 * LROW], Bl[128 * LROW];

  // staging: 2 threads per row, 16 k-elements (chunks 2p, 2p+1) each
  const int s_row = t >> 1;
  const int p = t & 1;
  const int hm = (s_row ^ (s_row >> 2)) & 3;
  const int wo0 = s_row * LROW + ((2 * p) ^ hm) * 8;
  const int wo1 = s_row * LROW + ((2 * p + 1) ^ hm) * 8;
  const int s_kh = p * 16;

  const bool aval = (i0 + s_row) < cnt;
  const int tok = aval ? (bucket[e * N_TOK + i0 + s_row] >> 1) : 0;
  const uint32_t* ap = x2 + (size_t)tok * DIM + s_kh;
  const uint32_t* bp = W1t + ((size_t)e * HID + n0 + s_row) * DIM + s_kh;

  f32x4 acc[4][4] = {};

  uint4 ar[4], br[4];
#pragma unroll
  for (int j = 0; j < 4; ++j) {
    ar[j] = *(const uint4*)(ap + j * 4);
    br[j] = *(const uint4*)(bp + j * 4);
  }

  // read bases: chunk kg at row (wr*64 + fl + f*16) lives at kg ^ h(fl)
  const int hf = (fl ^ (fl >> 2)) & 3;
  const int abase = (wr * 64 + fl) * LROW + ((kg ^ hf)) * 8;
  const int bbase = (wc * 64 + fl) * LROW + ((kg ^ hf)) * 8;

  for (int k0 = 0; k0 < DIM; k0 += 32) {
    __syncthreads();
    {
      u16x8 h0, l0, h1, l1;
      unpack8(ar[0], ar[1], h0, l0);
      unpack8(ar[2], ar[3], h1, l1);
      *(u16x8*)&Ah[wo0] = h0;  *(u16x8*)&Ah[wo1] = h1;
      *(u16x8*)&Al[wo0] = l0;  *(u16x8*)&Al[wo1] = l1;
      unpack8(br[0], br[1], h0, l0);
      unpack8(br[2], br[3], h1, l1);
      *(u16x8*)&Bh[wo0] = h0;  *(u16x8*)&Bh[wo1] = h1;
      *(u16x8*)&Bl[wo0] = l0;  *(u16x8*)&Bl[wo1] = l1;
    }
    __syncthreads();
    if (k0 + 32 < DIM) {
#pragma unroll
      for (int j = 0; j < 4; ++j) {
        ar[j] = *(const uint4*)(ap + k0 + 32 + j * 4);
        br[j] = *(const uint4*)(bp + k0 + 32 + j * 4);
      }
    }
    half8 ah[4], al_[4], bh[4], bl_[4];
#pragma unroll
    for (int f = 0; f < 4; ++f) {
      ah[f]  = *(const half8*)&Ah[abase + f * 16 * LROW];
      al_[f] = *(const half8*)&Al[abase + f * 16 * LROW];
      bh[f]  = *(const half8*)&Bh[bbase + f * 16 * LROW];
      bl_[f] = *(const half8*)&Bl[bbase + f * 16 * LROW];
    }
    // 3-term split product; dependent MFMAs on same acc separated by 4
#pragma unroll
    for (int fc = 0; fc < 4; ++fc) {
#pragma unroll
      for (int fr = 0; fr < 4; ++fr)
        acc[fr][fc] = __builtin_amdgcn_mfma_f32_16x16x32_f16(ah[fr], bh[fc], acc[fr][fc], 0, 0, 0);
#pragma unroll
      for (int fr = 0; fr < 4; ++fr)
        acc[fr][fc] = __builtin_amdgcn_mfma_f32_16x16x32_f16(al_[fr], bh[fc], acc[fr][fc], 0, 0, 0);
#pragma unroll
      for (int fr = 0; fr < 4; ++fr)
        acc[fr][fc] = __builtin_amdgcn_mfma_f32_16x16x32_f16(ah[fr], bl_[fc], acc[fr][fc], 0, 0, 0);
    }
  }

  // epilogue: bias + gelu + split-pack (C/D map: col=lane&15, row=kg*4+q)
  const int hbase = offs[e] + i0;
  const float* b1e = b1 + (size_t)e * HID;
  float bs[4];
#pragma unroll
  for (int fc = 0; fc < 4; ++fc) bs[fc] = b1e[n0 + wc * 64 + fc * 16 + fl];
#pragma unroll
  for (int fr = 0; fr < 4; ++fr)
#pragma unroll
    for (int q = 0; q < 4; ++q) {
      const int lr = wr * 64 + fr * 16 + kg * 4 + q;
      if (i0 + lr < cnt) {
        uint32_t* hr = h2 + (size_t)(hbase + lr) * HID + n0 + wc * 64 + fl;
#pragma unroll
        for (int fc = 0; fc < 4; ++fc)
          hr[fc * 16] = split_pack(gelu_exact(acc[fr][fc][q] + bs[fc]));
      }
    }
}

// pass 2 (split-K x4): y[tok,:] += w * (h[slot] @ W2[e] + b2[e])
__global__ __launch_bounds__(256) void mlp2_mfma(
    const uint32_t* __restrict__ h2, const uint32_t* __restrict__ W2t,
    const float* __restrict__ b2, const int* __restrict__ bucket,
    const int* __restrict__ counts, const int* __restrict__ offs,
    const float* __restrict__ wts, float* __restrict__ y)
{
  const int e = blockIdx.z;
  const int cnt = counts[e];
  const int i0 = blockIdx.y * 128;
  if (i0 >= cnt) return;
  const int n0 = (blockIdx.x & 3) * 128;   // n-block
  const int kc = blockIdx.x >> 2;          // k-chunk, 0..KS-1
  const int kb = kc * (HID / KS);          // k base
  const int t = threadIdx.x;
  const int lane = t & 63, w = t >> 6;
  const int wr = w >> 1, wc = w & 1;
  const int fl = lane & 15, kg = lane >> 4;

  __shared__ unsigned short Ah[128 * LROW], Al[128 * LROW];
  __shared__ unsigned short Bh[128 * LROW], Bl[128 * LROW];

  const int s_row = t >> 1;
  const int p = t & 1;
  const int hm = (s_row ^ (s_row >> 2)) & 3;
  const int wo0 = s_row * LROW + ((2 * p) ^ hm) * 8;
  const int wo1 = s_row * LROW + ((2 * p + 1) ^ hm) * 8;
  const int s_kh = p * 16;

  const bool aval = (i0 + s_row) < cnt;
  const int aslot = offs[e] + (aval ? i0 + s_row : 0);
  const uint32_t* ap = h2 + (size_t)aslot * HID + kb + s_kh;
  const uint32_t* bp = W2t + ((size_t)e * DIM + n0 + s_row) * HID + kb + s_kh;

  f32x4 acc[4][4] = {};

  uint4 ar[4], br[4];
#pragma unroll
  for (int j = 0; j < 4; ++j) {
    ar[j] = *(const uint4*)(ap + j * 4);
    br[j] = *(const uint4*)(bp + j * 4);
  }

  const int hf = (fl ^ (fl >> 2)) & 3;
  const int abase = (wr * 64 + fl) * LROW + ((kg ^ hf)) * 8;
  const int bbase = (wc * 64 + fl) * LROW + ((kg ^ hf)) * 8;

  for (int k0 = 0; k0 < HID / KS; k0 += 32) {
    __syncthreads();
    {
      u16x8 h0, l0, h1, l1;
      unpack8(ar[0], ar[1], h0, l0);
      unpack8(ar[2], ar[3], h1, l1);
      *(u16x8*)&Ah[wo0] = h0;  *(u16x8*)&Ah[wo1] = h1;
      *(u16x8*)&Al[wo0] = l0;  *(u16x8*)&Al[wo1] = l1;
      unpack8(br[0], br[1], h0, l0);
      unpack8(br[2], br[3], h1, l1);
      *(u16x8*)&Bh[wo0] = h0;  *(u16x8*)&Bh[wo1] = h1;
      *(u16x8*)&Bl[wo0] = l0;  *(u16x8*)&Bl[wo1] = l1;
    }
    __syncthreads();
    if (k0 + 32 < HID / KS) {
#pragma unroll
      for (int j = 0; j < 4; ++j) {
        ar[j] = *(const uint4*)(ap + k0 + 32 + j * 4);
        br[j] = *(const uint4*)(bp + k0 + 32 + j * 4);
      }
    }
    half8 ah[4], al_[4], bh[4], bl_[4];
#pragma unroll
    for (int f = 0; f < 4; ++f) {
      ah[f]  = *(const half8*)&Ah[abase + f * 16 * LROW];
      al_[f] = *(const half8*)&Al[abase + f * 16 * LROW];
      bh[f]  = *(const half8*)&Bh[bbase + f * 16 * LROW];
      bl_[f] = *(const half8*)&Bl[bbase + f * 16 * LROW];
    }
#pragma unroll
    for (int fc = 0; fc < 4; ++fc) {
#pragma unroll
      for (int fr = 0; fr < 4; ++fr)
        acc[fr][fc] = __builtin_amdgcn_mfma_f32_16x16x32_f16(ah[fr], bh[fc], acc[fr][fc], 0, 0, 0);
#pragma unroll
      for (int fr = 0; fr < 4; ++fr)
        acc[fr][fc] = __builtin_amdgcn_mfma_f32_16x16x32_f16(al_[fr], bh[fc], acc[fr][fc], 0, 0, 0);
#pragma unroll
      for (int fr = 0; fr < 4; ++fr)
        acc[fr][fc] = __builtin_amdgcn_mfma_f32_16x16x32_f16(ah[fr], bl_[fc], acc[fr][fc], 0, 0, 0);
    }
  }

  // bias added exactly once (kc==0 block)
  const float* b2e = b2 + (size_t)e * DIM;
  float bs[4];
#pragma unroll
  for (int fc = 0; fc < 4; ++fc)
    bs[fc] = (kc == 0) ? b2e[n0 + wc * 64 + fc * 16 + fl] : 0.0f;
#pragma unroll
  for (int fr = 0; fr < 4; ++fr)
#pragma unroll
    for (int q = 0; q < 4; ++q) {
      const int lr = wr * 64 + fr * 16 + kg * 4 + q;
      if (i0 + lr < cnt) {
        const int ent = bucket[e * N_TOK + i0 + lr];
        const int tk = ent >> 1;
        const float wgt = wts[ent];
        float* yr = y + (size_t)tk * DIM + n0 + wc * 64 + fl;
#pragma unroll
        for (int fc = 0; fc < 4; ++fc)
          atomicAdd(yr + fc * 16, wgt * (acc[fr][fc][q] + bs[fc]));
      }
    }
}

extern "C" void kernel_launch(void* const* d_in, const int* in_sizes, int n_in,
                              void* d_out, int out_size, void* d_ws, size_t ws_size,
                              hipStream_t stream) {
  const float* x   = (const float*)d_in[0];
  const float* mus = (const float*)d_in[1];
  const float* ls  = (const float*)d_in[2];
  const float* W1  = (const float*)d_in[3];
  const float* b1  = (const float*)d_in[4];
  const float* W2  = (const float*)d_in[5];
  const float* b2  = (const float*)d_in[6];

  float* out      = (float*)d_out;
  float* y        = out;                           // [N_TOK, DIM]
  float* out_logp = out + (size_t)N_TOK * DIM;     // [N_TOK, NE]
  float* out_w    = out_logp + (size_t)N_TOK * NE; // [N_TOK, 2]
  float* out_idx  = out_w + (size_t)N_TOK * 2;     // [N_TOK, 2] (as float)

  // workspace layout
  uint32_t* W1t = (uint32_t*)d_ws;                  // [NE][HID][DIM] u32  33.5MB
  uint32_t* W2t = W1t + (size_t)NE * HID * DIM;     // [NE][DIM][HID] u32  33.5MB
  uint32_t* h2  = W2t + (size_t)NE * DIM * HID;     // [NSLOT][HID]  u32   67.1MB
  uint32_t* x2  = h2 + (size_t)NSLOT * HID;         // [N_TOK][DIM]  u32    8.4MB
  int* bucket   = (int*)(x2 + (size_t)N_TOK * DIM); // [NE][N_TOK]
  float* wts    = (float*)(bucket + NE * N_TOK);    // [N_TOK][2]
  int* counts   = (int*)(wts + 2 * N_TOK);          // [NE]
  int* offs     = counts + NE;                      // [NE]

  hipMemsetAsync(y, 0, (size_t)N_TOK * DIM * sizeof(float), stream);
  hipMemsetAsync(counts, 0, NE * sizeof(int), stream);

  router_kernel<<<N_TOK / 4, 256, 0, stream>>>(x, mus, ls, out_logp, out_w,
                                               out_idx, wts, bucket, counts);
  scan_kernel<<<1, 1, 0, stream>>>(counts, offs);

  x_split<<<(N_TOK * DIM / 4) / 256, 256, 0, stream>>>(x, x2);
  transpose_split<<<dim3(HID / 64, DIM / 64, NE), 256, 0, stream>>>(W1, W1t, DIM, HID);
  transpose_split<<<dim3(DIM / 64, HID / 64, NE), 256, 0, stream>>>(W2, W2t, HID, DIM);

  mlp1_mfma<<<dim3(HID / 128, N_TOK / 128, NE), 256, 0, stream>>>(
      x2, W1t, b1, bucket, counts, offs, h2);
  mlp2_mfma<<<dim3((DIM / 128) * KS, N_TOK / 128, NE), 256, 0, stream>>>(
      h2, W2t, b2, bucket, counts, offs, wts, y);
}